// Round 6
// baseline (33.242 us; speedup 1.0000x reference)
//
#include <hip/hip_runtime.h>

// VQWeightedAvgPool: out[b,d] = sum_l w[b,l] * feat[b, N-1, l, d]
// w[b,l] = 1 / (n_seg_b * seg_len_b(l)) for l < len_b, else 0.
// feat (B=16, N=13, L=2048, D=768) f32; lengths (B,) int; vq (B, L, 2) int.

#define L_SEQ 2048
#define D_DIM 768
#define N_DIM 13
#define B_DIM 16
#define BLK_A 256
#define PER_A 8                  // 2048 / 256
#define LT 32                    // L-rows per pooling tile
#define MAX_TILES (L_SEQ / LT)   // 64
#define GRID_B (B_DIM * MAX_TILES)  // 1024: upper bound on valid tiles

// ---------------- Kernel A: per-batch segment weights (+ zero out) ----------
// 16 blocks x 256 threads (exact R3 structure: best measured).
__global__ __launch_bounds__(BLK_A) void vq_weights_kernel(
    const int* __restrict__ lengths,
    const int* __restrict__ vq,
    float* __restrict__ w,
    float* __restrict__ out) {
  __shared__ int s_seg[L_SEQ];   // inclusive cumsum of boundary (= seg_id+1)
  __shared__ int s_cnt[L_SEQ];   // per-segment valid counts
  __shared__ int s_wsum[4];

  const int b = blockIdx.x;
  const int tid = threadIdx.x;
  const int lane = tid & 63;
  const int wid = tid >> 6;
  const int len = lengths[b];
  const int* vqb = vq + (size_t)b * L_SEQ * 2;

  // zero this batch's output slice (replaces hipMemsetAsync launch)
  for (int d = tid; d < D_DIM; d += BLK_A) out[(size_t)b * D_DIM + d] = 0.0f;

  // vectorized pair loads: thread t owns l in [8t, 8t+8)
  int4 q[4];
  const int4* v4 = (const int4*)vqb;
#pragma unroll
  for (int i = 0; i < 4; ++i) q[i] = v4[4 * tid + i];
  int px = 0, py = 0;
  if (tid > 0) {
    const int2 pp = *(const int2*)(vqb + 16 * tid - 2);  // pair of l = 8t-1
    px = pp.x; py = pp.y;
  }
  int cx[PER_A], cy[PER_A];
  cx[0] = q[0].x; cy[0] = q[0].y; cx[1] = q[0].z; cy[1] = q[0].w;
  cx[2] = q[1].x; cy[2] = q[1].y; cx[3] = q[1].z; cy[3] = q[1].w;
  cx[4] = q[2].x; cy[4] = q[2].y; cx[5] = q[2].z; cy[5] = q[2].w;
  cx[6] = q[3].x; cy[6] = q[3].y; cx[7] = q[3].z; cy[7] = q[3].w;

  int flags[PER_A];
  const int base = tid * PER_A;
  int lsum = 0;
#pragma unroll
  for (int i = 0; i < PER_A; ++i) {
    const int l = base + i;
    int bd = 0;
    if (l < len) {
      if (l == 0) {
        bd = 1;
      } else {
        const int prx = (i == 0) ? px : cx[i - 1];
        const int pry = (i == 0) ? py : cy[i - 1];
        bd = (cx[i] != prx) || (cy[i] != pry);
      }
    }
    lsum += bd;
    flags[i] = lsum;
  }

  int v = lsum;
  for (int off = 1; off < 64; off <<= 1) {
    int n = __shfl_up(v, off, 64);
    if (lane >= off) v += n;
  }
  if (lane == 63) s_wsum[wid] = v;
  __syncthreads();

  int woff = 0;
#pragma unroll
  for (int i = 0; i < 4; ++i)
    if (i < wid) woff += s_wsum[i];
  const int nseg = s_wsum[0] + s_wsum[1] + s_wsum[2] + s_wsum[3];
  const int excl = woff + (v - lsum);

#pragma unroll
  for (int i = 0; i < PER_A; ++i) s_seg[base + i] = excl + flags[i];
  for (int l = tid; l < L_SEQ; l += BLK_A) s_cnt[l] = 0;
  __syncthreads();

  for (int l = tid; l < L_SEQ; l += BLK_A)
    if (l < len) atomicAdd(&s_cnt[s_seg[l] - 1], 1);
  __syncthreads();

  const float nsegf = (float)nseg;
  for (int l = tid; l < L_SEQ; l += BLK_A) {
    float wv = 0.0f;
    if (l < len) {
      const float denom = fmaxf(nsegf * (float)s_cnt[s_seg[l] - 1], 1.0f);
      wv = 1.0f / denom;
    }
    w[(size_t)b * L_SEQ + l] = wv;
  }
}

// ---------------- Kernel B: weighted pooling, flat balanced tile map --------
// 1024 blocks x 192 threads. Block i owns global valid-tile index i:
// prefix over ceil(len_b/32) maps i -> (b, t). At most ONE tile per block ->
// no sequential-tile tail. Thread owns float4 at d = 4*tid (768 = 192*4).
__global__ __launch_bounds__(192) void vq_pool_kernel(
    const float* __restrict__ feat,
    const int* __restrict__ lengths,
    const float* __restrict__ w,
    float* __restrict__ out) {
  const int gidx = blockIdx.x;
  const int tid = threadIdx.x;

  // flat valid-tile index -> (batch, tile). 16-step wave-uniform scan.
  int b = -1, t = 0, acc = 0;
#pragma unroll
  for (int bb = 0; bb < B_DIM; ++bb) {
    const int len = lengths[bb];
    int ntb = (len + LT - 1) / LT;
    ntb = ntb > MAX_TILES ? MAX_TILES : ntb;
    if (b < 0 && gidx < acc + ntb) {
      b = bb;
      t = gidx - acc;
    }
    acc += ntb;
  }
  if (b < 0) return;  // gidx >= total valid tiles

  const int l0 = t * LT;
  const float* wb = w + (size_t)b * L_SEQ + l0;

  // tile weights (uniform across lanes); trailing zeros handle len tail
  const float4* wb4 = (const float4*)wb;
  float wl[LT];
#pragma unroll
  for (int i = 0; i < LT / 4; ++i) {
    const float4 wv = wb4[i];
    wl[4 * i + 0] = wv.x;
    wl[4 * i + 1] = wv.y;
    wl[4 * i + 2] = wv.z;
    wl[4 * i + 3] = wv.w;
  }

  // 32 independent unconditional float4 row loads -> deep MLP
  const float* basep =
      feat + (((size_t)b * N_DIM + (N_DIM - 1)) * L_SEQ + l0) * D_DIM + tid * 4;
  float4 acc4 = make_float4(0.f, 0.f, 0.f, 0.f);
#pragma unroll
  for (int i = 0; i < LT; ++i) {
    const float4 vx = *(const float4*)(basep + (size_t)i * D_DIM);
    acc4.x += wl[i] * vx.x;
    acc4.y += wl[i] * vx.y;
    acc4.z += wl[i] * vx.z;
    acc4.w += wl[i] * vx.w;
  }

  float* o = out + (size_t)b * D_DIM + tid * 4;
  atomicAdd(o + 0, acc4.x);
  atomicAdd(o + 1, acc4.y);
  atomicAdd(o + 2, acc4.z);
  atomicAdd(o + 3, acc4.w);
}

extern "C" void kernel_launch(void* const* d_in, const int* in_sizes, int n_in,
                              void* d_out, int out_size, void* d_ws, size_t ws_size,
                              hipStream_t stream) {
  const float* feat = (const float*)d_in[0];
  const int* lengths = (const int*)d_in[1];
  const int* vq = (const int*)d_in[2];
  float* out = (float*)d_out;
  float* w = (float*)d_ws;  // B*L floats = 128 KiB

  const int B = in_sizes[1];  // 16

  vq_weights_kernel<<<B, BLK_A, 0, stream>>>(lengths, vq, w, out);
  vq_pool_kernel<<<GRID_B, 192, 0, stream>>>(feat, lengths, w, out);
}

// Round 7
// 24.897 us; speedup vs baseline: 1.3352x; 1.3352x over previous
//
#include <hip/hip_runtime.h>

// VQWeightedAvgPool: out[b,d] = sum_l w[b,l] * feat[b, N-1, l, d]
// w[b,l] = 1 / (n_seg_b * seg_len_b(l)) for l < len_b, else 0.
// feat (B=16, N=13, L=2048, D=768) f32; lengths (B,) int; vq (B, L, 2) int.
//
// 3 kernels: A (weights, 16 blocks), B (pooling partials, R3 structure,
// NO atomics - plain stores to ws), C (32-way reduce -> out).

#define L_SEQ 2048
#define D_DIM 768
#define N_DIM 13
#define B_DIM 16
#define BLK_A 256
#define PER_A 8                  // 2048 / 256
#define LT 32                    // L-rows per pooling tile
#define MAX_TILES (L_SEQ / LT)   // 64
#define SUBS 32                  // pooling blocks per batch
#define GRID_B (B_DIM * SUBS)    // 512

// ---------------- Kernel A: per-batch segment weights ----------------
__global__ __launch_bounds__(BLK_A) void vq_weights_kernel(
    const int* __restrict__ lengths,
    const int* __restrict__ vq,
    float* __restrict__ w) {
  __shared__ int s_seg[L_SEQ];   // inclusive cumsum of boundary (= seg_id+1)
  __shared__ int s_cnt[L_SEQ];   // per-segment valid counts
  __shared__ int s_wsum[4];

  const int b = blockIdx.x;
  const int tid = threadIdx.x;
  const int lane = tid & 63;
  const int wid = tid >> 6;
  const int len = lengths[b];
  const int* vqb = vq + (size_t)b * L_SEQ * 2;

  // vectorized pair loads: thread t owns l in [8t, 8t+8)
  int4 q[4];
  const int4* v4 = (const int4*)vqb;
#pragma unroll
  for (int i = 0; i < 4; ++i) q[i] = v4[4 * tid + i];
  int px = 0, py = 0;
  if (tid > 0) {
    const int2 pp = *(const int2*)(vqb + 16 * tid - 2);  // pair of l = 8t-1
    px = pp.x; py = pp.y;
  }
  int cx[PER_A], cy[PER_A];
  cx[0] = q[0].x; cy[0] = q[0].y; cx[1] = q[0].z; cy[1] = q[0].w;
  cx[2] = q[1].x; cy[2] = q[1].y; cx[3] = q[1].z; cy[3] = q[1].w;
  cx[4] = q[2].x; cy[4] = q[2].y; cx[5] = q[2].z; cy[5] = q[2].w;
  cx[6] = q[3].x; cy[6] = q[3].y; cx[7] = q[3].z; cy[7] = q[3].w;

  int flags[PER_A];
  const int base = tid * PER_A;
  int lsum = 0;
#pragma unroll
  for (int i = 0; i < PER_A; ++i) {
    const int l = base + i;
    int bd = 0;
    if (l < len) {
      if (l == 0) {
        bd = 1;
      } else {
        const int prx = (i == 0) ? px : cx[i - 1];
        const int pry = (i == 0) ? py : cy[i - 1];
        bd = (cx[i] != prx) || (cy[i] != pry);
      }
    }
    lsum += bd;
    flags[i] = lsum;
  }

  int v = lsum;
  for (int off = 1; off < 64; off <<= 1) {
    int n = __shfl_up(v, off, 64);
    if (lane >= off) v += n;
  }
  if (lane == 63) s_wsum[wid] = v;
  __syncthreads();

  int woff = 0;
#pragma unroll
  for (int i = 0; i < 4; ++i)
    if (i < wid) woff += s_wsum[i];
  const int nseg = s_wsum[0] + s_wsum[1] + s_wsum[2] + s_wsum[3];
  const int excl = woff + (v - lsum);

#pragma unroll
  for (int i = 0; i < PER_A; ++i) s_seg[base + i] = excl + flags[i];
  for (int l = tid; l < L_SEQ; l += BLK_A) s_cnt[l] = 0;
  __syncthreads();

  for (int l = tid; l < L_SEQ; l += BLK_A)
    if (l < len) atomicAdd(&s_cnt[s_seg[l] - 1], 1);
  __syncthreads();

  const float nsegf = (float)nseg;
  for (int l = tid; l < L_SEQ; l += BLK_A) {
    float wv = 0.0f;
    if (l < len) {
      const float denom = fmaxf(nsegf * (float)s_cnt[s_seg[l] - 1], 1.0f);
      wv = 1.0f / denom;
    }
    w[(size_t)b * L_SEQ + l] = wv;
  }
}

// ---------------- Kernel B: pooling partials (R3 structure, no atomics) -----
// 512 blocks: (b = blk>>5, sub = blk&31). Block handles tiles
// t = sub, sub+32, ... < nt; accumulates in regs; ONE plain f4 store to ws.
// 192 threads: thread owns float4 at d = 4*tid (768 = 192*4).
__global__ __launch_bounds__(192) void vq_pool_kernel(
    const float* __restrict__ feat,
    const int* __restrict__ lengths,
    const float* __restrict__ w,
    float* __restrict__ part) {
  const int b = blockIdx.x >> 5;
  const int sub = blockIdx.x & (SUBS - 1);
  const int tid = threadIdx.x;
  const int len = lengths[b];
  int nt = (len + LT - 1) / LT;
  if (nt > MAX_TILES) nt = MAX_TILES;

  const float* fb = feat + ((size_t)b * N_DIM + (N_DIM - 1)) * L_SEQ * D_DIM;
  const float* wb = w + (size_t)b * L_SEQ;

  float4 acc = make_float4(0.f, 0.f, 0.f, 0.f);
  for (int t = sub; t < nt; t += SUBS) {
    const int l0 = t * LT;
    const float4* wb4 = (const float4*)(wb + l0);
    float wl[LT];
#pragma unroll
    for (int i = 0; i < LT / 4; ++i) {
      const float4 wv = wb4[i];
      wl[4 * i + 0] = wv.x;
      wl[4 * i + 1] = wv.y;
      wl[4 * i + 2] = wv.z;
      wl[4 * i + 3] = wv.w;
    }
    const float* basep = fb + (size_t)l0 * D_DIM + tid * 4;
#pragma unroll
    for (int i = 0; i < LT; ++i) {
      const float4 vx = *(const float4*)(basep + (size_t)i * D_DIM);
      acc.x += wl[i] * vx.x;
      acc.y += wl[i] * vx.y;
      acc.z += wl[i] * vx.z;
      acc.w += wl[i] * vx.w;
    }
  }

  // plain coalesced store of this block's partial (always, even if zero)
  *(float4*)(part + (size_t)blockIdx.x * D_DIM + tid * 4) = acc;
}

// ---------------- Kernel C: reduce 32 partials -> out ----------------
// 48 blocks x 64 threads; global f4-slot = bid*64+tid in [0, 3072).
__global__ __launch_bounds__(64) void vq_reduce_kernel(
    const float* __restrict__ part,
    float* __restrict__ out) {
  const int slot = blockIdx.x * 64 + threadIdx.x;  // f4 index into out
  const int b = slot / (D_DIM / 4);
  const int d4 = slot - b * (D_DIM / 4);

  const float* p = part + ((size_t)b * SUBS) * D_DIM + d4 * 4;
  float4 acc = make_float4(0.f, 0.f, 0.f, 0.f);
#pragma unroll
  for (int s = 0; s < SUBS; ++s) {
    const float4 v = *(const float4*)(p + (size_t)s * D_DIM);
    acc.x += v.x;
    acc.y += v.y;
    acc.z += v.z;
    acc.w += v.w;
  }
  *(float4*)(out + (size_t)b * D_DIM + d4 * 4) = acc;
}

extern "C" void kernel_launch(void* const* d_in, const int* in_sizes, int n_in,
                              void* d_out, int out_size, void* d_ws, size_t ws_size,
                              hipStream_t stream) {
  const float* feat = (const float*)d_in[0];
  const int* lengths = (const int*)d_in[1];
  const int* vq = (const int*)d_in[2];
  float* out = (float*)d_out;
  float* w = (float*)d_ws;                          // B*L floats = 128 KiB
  float* part = w + (size_t)B_DIM * L_SEQ;          // 512*768 floats = 1.5 MiB

  const int B = in_sizes[1];  // 16

  vq_weights_kernel<<<B, BLK_A, 0, stream>>>(lengths, vq, w);
  vq_pool_kernel<<<GRID_B, 192, 0, stream>>>(feat, lengths, w, part);
  vq_reduce_kernel<<<(B * D_DIM / 4) / 64, 64, 0, stream>>>(part, out);
}